// Round 15
// baseline (488.996 us; speedup 1.0000x reference)
//
#include <hip/hip_runtime.h>
#include <hip/hip_fp16.h>

// TemporalEMA: out = ALPHA * bilinear_warp(prev, mv) + (1-ALPHA) * cur
// R15 = R14 inner kernel (named-reg/asm forced-flight loads, pixel-major f16
// ws) on 64x4 tiles / 256-thread blocks / grid 32400: occupancy experiment.
// R14 null result killed the MLP theory (334->337, FETCH identical): the wall
// is per-CU L1-miss service (~6.6 cy/miss at 63% occ). Only untested lever is
// more resident waves -> more in-use MSHRs. R4 (256-thr direct) hit 84% occ.

#define ALPHA 0.85f

constexpr int Bc = 4;
constexpr int Cc = 16;
constexpr int Hc = 1080;
constexpr int Wc = 1920;
constexpr size_t PLANE = (size_t)Hc * Wc;
constexpr size_t WS_NEED = (size_t)Bc * PLANE * Cc * sizeof(__half);  // 265 MB

constexpr int TW = 64;
constexpr int TH = 4;                 // 256-thread block, 4 waves
constexpr int NX = Wc / TW;           // 30
constexpr int NY = Hc / TH;           // 270
constexpr int NBLK = Bc * NY * NX;    // 32400
constexpr int NXCD = 8;
constexpr int CHUNK = NBLK / NXCD;    // 4050 (divisible -> bijective)

constexpr int BLK_PER_B = (int)(PLANE / 256);  // 8100 (repack, 256 thr)

typedef float f2 __attribute__((ext_vector_type(2)));
typedef _Float16 h8 __attribute__((ext_vector_type(8)));

// ---------------- kernel 1: repack prev -> [B,H,W,C16] f16 ----------------
__global__ __launch_bounds__(256) void TemporalEMA_repack_kernel(
    const float* __restrict__ prev, __half* __restrict__ ws)
{
    const int b  = blockIdx.x / BLK_PER_B;
    const int wb = blockIdx.x % BLK_PER_B;
    const size_t pix = (size_t)wb * 256 + threadIdx.x;   // within plane

    const float* src = prev + (size_t)b * Cc * PLANE + pix;
    h8 v0, v1;
    #pragma unroll
    for (int c = 0; c < 8; ++c)
        v0[c] = (_Float16)src[(size_t)c * PLANE];
    #pragma unroll
    for (int c = 0; c < 8; ++c)
        v1[c] = (_Float16)src[(size_t)(8 + c) * PLANE];

    h8* dst = (h8*)(ws + ((size_t)b * PLANE + pix) * Cc);
    __builtin_nontemporal_store(v0, &dst[0]);
    __builtin_nontemporal_store(v1, &dst[1]);
}

// ---------------- kernel 2: gather + blend, 64x4 tile, forced-flight ----------------
__global__ __launch_bounds__(256) void TemporalEMA_73194832658797_kernel(
    const float* __restrict__ cur,
    const __half* __restrict__ wsp,
    const float* __restrict__ mv,
    float* __restrict__ out)
{
    const int bid  = blockIdx.x;
    const int work = (bid % NXCD) * CHUNK + bid / NXCD;   // chunked XCD swizzle

    const int tx  = work % NX;
    const int rem = work / NX;
    const int ty  = rem % NY;
    const int b   = rem / NY;

    const int lw = threadIdx.x & 63;
    const int lh = threadIdx.x >> 6;        // 0..3
    const int w  = tx * TW + lw;
    const int h  = ty * TH + lh;

    const size_t pix = (size_t)h * Wc + w;

    const float mvx = __builtin_nontemporal_load(&mv[((size_t)b * 2 + 0) * PLANE + pix]);
    const float mvy = __builtin_nontemporal_load(&mv[((size_t)b * 2 + 1) * PLANE + pix]);

    const float sxk = (float)(Wc - 1) / (float)Wc;
    const float syk = (float)(Hc - 1) / (float)Hc;
    float px = fminf(fmaxf((float)w - mvx * sxk, 0.0f), (float)(Wc - 1));
    float py = fminf(fmaxf((float)h - mvy * syk, 0.0f), (float)(Hc - 1));

    const int x0 = min((int)floorf(px), Wc - 2);   // weights absorb border clamp
    const int y0 = min((int)floorf(py), Hc - 2);
    const float wx = px - (float)x0;
    const float wy = py - (float)y0;

    const float w00 = (1.0f - wx) * (1.0f - wy);
    const float w01 = wx * (1.0f - wy);
    const float w10 = (1.0f - wx) * wy;
    const float w11 = wx * wy;

    // ---- issue ALL 24 loads via inline asm (distinct live registers) ----
    const size_t p00 = ((size_t)b * PLANE + (size_t)y0 * Wc + x0) * Cc;
    const __half* gp0 = wsp + p00;                     // row y0:   v00|v01 (64B)
    const __half* gp1 = gp0 + (size_t)Wc * Cc;         // row y0+1: v10|v11 (64B)

    h8 a0, a1, a2, a3, b0, b1, b2, b3;
    asm volatile("global_load_dwordx4 %0, %1, off"           : "=&v"(a0) : "v"(gp0));
    asm volatile("global_load_dwordx4 %0, %1, off offset:16" : "=&v"(a1) : "v"(gp0));
    asm volatile("global_load_dwordx4 %0, %1, off offset:32" : "=&v"(a2) : "v"(gp0));
    asm volatile("global_load_dwordx4 %0, %1, off offset:48" : "=&v"(a3) : "v"(gp0));
    asm volatile("global_load_dwordx4 %0, %1, off"           : "=&v"(b0) : "v"(gp1));
    asm volatile("global_load_dwordx4 %0, %1, off offset:16" : "=&v"(b1) : "v"(gp1));
    asm volatile("global_load_dwordx4 %0, %1, off offset:32" : "=&v"(b2) : "v"(gp1));
    asm volatile("global_load_dwordx4 %0, %1, off offset:48" : "=&v"(b3) : "v"(gp1));

    const size_t cb0 = (size_t)b * Cc * PLANE + pix;
    const float* cp = cur + cb0;
    float cu0, cu1, cu2, cu3, cu4, cu5, cu6, cu7;
    float cu8, cu9, cu10, cu11, cu12, cu13, cu14, cu15;
#define CURLOAD(i, dst) \
    asm volatile("global_load_dword %0, %1, off" : "=&v"(dst) : "v"(cp + (size_t)(i) * PLANE))
    CURLOAD(0, cu0);   CURLOAD(1, cu1);   CURLOAD(2, cu2);   CURLOAD(3, cu3);
    CURLOAD(4, cu4);   CURLOAD(5, cu5);   CURLOAD(6, cu6);   CURLOAD(7, cu7);
    CURLOAD(8, cu8);   CURLOAD(9, cu9);   CURLOAD(10, cu10); CURLOAD(11, cu11);
    CURLOAD(12, cu12); CURLOAD(13, cu13); CURLOAD(14, cu14); CURLOAD(15, cu15);
#undef CURLOAD

    asm volatile("s_waitcnt vmcnt(0)" ::: "memory");
    __builtin_amdgcn_sched_barrier(0);    // rule #18: consumers must not hoist

    // ---- consume (compile-time indices only) ----
    float* op = out + cb0;
#define BLEND(c, t00, t01, t10, t11, cuv)                                       \
    __builtin_nontemporal_store(                                                \
        ALPHA * ((float)(t00) * w00 + (float)(t01) * w01 +                      \
                 (float)(t10) * w10 + (float)(t11) * w11) +                     \
        (1.0f - ALPHA) * (cuv), &op[(size_t)(c) * PLANE])
    BLEND(0,  a0[0], a2[0], b0[0], b2[0], cu0);
    BLEND(1,  a0[1], a2[1], b0[1], b2[1], cu1);
    BLEND(2,  a0[2], a2[2], b0[2], b2[2], cu2);
    BLEND(3,  a0[3], a2[3], b0[3], b2[3], cu3);
    BLEND(4,  a0[4], a2[4], b0[4], b2[4], cu4);
    BLEND(5,  a0[5], a2[5], b0[5], b2[5], cu5);
    BLEND(6,  a0[6], a2[6], b0[6], b2[6], cu6);
    BLEND(7,  a0[7], a2[7], b0[7], b2[7], cu7);
    BLEND(8,  a1[0], a3[0], b1[0], b3[0], cu8);
    BLEND(9,  a1[1], a3[1], b1[1], b3[1], cu9);
    BLEND(10, a1[2], a3[2], b1[2], b3[2], cu10);
    BLEND(11, a1[3], a3[3], b1[3], b3[3], cu11);
    BLEND(12, a1[4], a3[4], b1[4], b3[4], cu12);
    BLEND(13, a1[5], a3[5], b1[5], b3[5], cu13);
    BLEND(14, a1[6], a3[6], b1[6], b3[6], cu14);
    BLEND(15, a1[7], a3[7], b1[7], b3[7], cu15);
#undef BLEND
}

// ---------------- fallback: R4 direct f32 gather (if ws too small) ----------------
__global__ __launch_bounds__(256) void TemporalEMA_fallback_kernel(
    const float* __restrict__ cur,
    const float* __restrict__ prev,
    const float* __restrict__ mv,
    float* __restrict__ out)
{
    const int bid  = blockIdx.x;
    const int work = (bid % NXCD) * CHUNK + bid / NXCD;
    const int tx  = work % NX;
    const int rem = work / NX;
    const int ty  = rem % NY;
    const int b   = rem / NY;
    const int lw = threadIdx.x & 63;
    const int lh = threadIdx.x >> 6;
    const int w  = tx * TW + lw;
    const int h  = ty * TH + lh;
    const size_t pix = (size_t)h * Wc + w;

    const float mvx = mv[((size_t)b * 2 + 0) * PLANE + pix];
    const float mvy = mv[((size_t)b * 2 + 1) * PLANE + pix];
    const float sxk = (float)(Wc - 1) / (float)Wc;
    const float syk = (float)(Hc - 1) / (float)Hc;
    float px = fminf(fmaxf((float)w - mvx * sxk, 0.0f), (float)(Wc - 1));
    float py = fminf(fmaxf((float)h - mvy * syk, 0.0f), (float)(Hc - 1));
    const int x0 = min((int)floorf(px), Wc - 2);
    const int y0 = min((int)floorf(py), Hc - 2);
    const float wx = px - (float)x0;
    const float wy = py - (float)y0;
    const float w00 = (1.0f - wx) * (1.0f - wy);
    const float w01 = wx * (1.0f - wy);
    const float w10 = (1.0f - wx) * wy;
    const float w11 = wx * wy;
    const size_t o0 = (size_t)y0 * Wc + x0;
    const size_t o1 = o0 + Wc;
    const size_t base_b = (size_t)b * Cc * PLANE;

    #pragma unroll
    for (int cg = 0; cg < Cc; cg += 4) {
        f2 p0[4], p1[4];
        float cu[4];
        #pragma unroll
        for (int j = 0; j < 4; ++j) {
            const size_t cb = base_b + (size_t)(cg + j) * PLANE;
            p0[j] = *(const f2*)(prev + cb + o0);
            p1[j] = *(const f2*)(prev + cb + o1);
            cu[j] = cur[cb + pix];
        }
        #pragma unroll
        for (int j = 0; j < 4; ++j) {
            const size_t cb = base_b + (size_t)(cg + j) * PLANE;
            const float warped = p0[j].x * w00 + p0[j].y * w01
                               + p1[j].x * w10 + p1[j].y * w11;
            out[cb + pix] = ALPHA * warped + (1.0f - ALPHA) * cu[j];
        }
    }
}

extern "C" void kernel_launch(void* const* d_in, const int* in_sizes, int n_in,
                              void* d_out, int out_size, void* d_ws, size_t ws_size,
                              hipStream_t stream) {
    const float* cur  = (const float*)d_in[0];
    const float* prev = (const float*)d_in[1];
    const float* mv   = (const float*)d_in[2];
    float* out = (float*)d_out;

    if (ws_size >= WS_NEED) {
        __half* ws = (__half*)d_ws;
        TemporalEMA_repack_kernel<<<Bc * BLK_PER_B, 256, 0, stream>>>(prev, ws);
        TemporalEMA_73194832658797_kernel<<<NBLK, 256, 0, stream>>>(cur, ws, mv, out);
    } else {
        TemporalEMA_fallback_kernel<<<NBLK, 256, 0, stream>>>(cur, prev, mv, out);
    }
}

// Round 16
// 479.102 us; speedup vs baseline: 1.0207x; 1.0207x over previous
//
#include <hip/hip_runtime.h>
#include <hip/hip_fp16.h>

// TemporalEMA: out = ALPHA * bilinear_warp(prev, mv) + (1-ALPHA) * cur
// FINAL (= R12, best measured: main 334 us, wall 480 us).
// Structure: repack prev [B,C,H,W]f32 -> ws [B,H,W,C16]f16 (one 64B record =
// all 16 channels of 2 adjacent px), then gather 2 records/px + EMA blend.
// Converged cost model (R12/R14/R15 agree within 3%): main is bound by
// unique-L1-miss-line service (~390 lines/wave at ~4-5 cy/CU), not BW/VALU.
// Tested-null levers: forced-flight asm loads (R14), occupancy via 256-thr
// (R15), x-coarsening (R9/R13), LDS staging (R3/R5). Repack is at ~1.15x its
// HBM floor. 64B-aligned duplicated records and fp8 priced out (L3/error).

#define ALPHA 0.85f

constexpr int Bc = 4;
constexpr int Cc = 16;
constexpr int Hc = 1080;
constexpr int Wc = 1920;
constexpr size_t PLANE = (size_t)Hc * Wc;
constexpr size_t WS_NEED = (size_t)Bc * PLANE * Cc * sizeof(__half);  // 265 MB

constexpr int TW = 64;
constexpr int TH = 8;                 // 512-thread block, 8 waves
constexpr int NX = Wc / TW;           // 30
constexpr int NY = Hc / TH;           // 135
constexpr int NBLK = Bc * NY * NX;    // 16200
constexpr int NXCD = 8;
constexpr int CHUNK = NBLK / NXCD;    // 2025 (divisible -> bijective)

constexpr int BLK_PER_B = (int)(PLANE / 256);  // 8100 (repack, 256 thr)

typedef float f2 __attribute__((ext_vector_type(2)));
typedef _Float16 h8 __attribute__((ext_vector_type(8)));

// ---------------- kernel 1: repack prev -> [B,H,W,C16] f16 ----------------
__global__ __launch_bounds__(256) void TemporalEMA_repack_kernel(
    const float* __restrict__ prev, __half* __restrict__ ws)
{
    const int b  = blockIdx.x / BLK_PER_B;
    const int wb = blockIdx.x % BLK_PER_B;
    const size_t pix = (size_t)wb * 256 + threadIdx.x;   // within plane

    const float* src = prev + (size_t)b * Cc * PLANE + pix;
    h8 v0, v1;
    #pragma unroll
    for (int c = 0; c < 8; ++c)
        v0[c] = (_Float16)src[(size_t)c * PLANE];
    #pragma unroll
    for (int c = 0; c < 8; ++c)
        v1[c] = (_Float16)src[(size_t)(8 + c) * PLANE];

    h8* dst = (h8*)(ws + ((size_t)b * PLANE + pix) * Cc);
    __builtin_nontemporal_store(v0, &dst[0]);
    __builtin_nontemporal_store(v1, &dst[1]);
}

// ---------------- kernel 2: gather + blend, 64x8 tile, register taps ----------------
__global__ __launch_bounds__(512, 2) void TemporalEMA_73194832658797_kernel(
    const float* __restrict__ cur,
    const __half* __restrict__ wsp,
    const float* __restrict__ mv,
    float* __restrict__ out)
{
    const int bid  = blockIdx.x;
    const int work = (bid % NXCD) * CHUNK + bid / NXCD;   // chunked XCD swizzle

    const int tx  = work % NX;
    const int rem = work / NX;
    const int ty  = rem % NY;
    const int b   = rem / NY;

    const int lw = threadIdx.x & 63;
    const int lh = threadIdx.x >> 6;        // 0..7
    const int w  = tx * TW + lw;
    const int h  = ty * TH + lh;

    const size_t pix = (size_t)h * Wc + w;

    const float mvx = __builtin_nontemporal_load(&mv[((size_t)b * 2 + 0) * PLANE + pix]);
    const float mvy = __builtin_nontemporal_load(&mv[((size_t)b * 2 + 1) * PLANE + pix]);

    const float sxk = (float)(Wc - 1) / (float)Wc;
    const float syk = (float)(Hc - 1) / (float)Hc;
    float px = fminf(fmaxf((float)w - mvx * sxk, 0.0f), (float)(Wc - 1));
    float py = fminf(fmaxf((float)h - mvy * syk, 0.0f), (float)(Hc - 1));

    const int x0 = min((int)floorf(px), Wc - 2);   // weights absorb border clamp
    const int y0 = min((int)floorf(py), Hc - 2);
    const float wx = px - (float)x0;
    const float wy = py - (float)y0;

    const float w00 = (1.0f - wx) * (1.0f - wy);
    const float w01 = wx * (1.0f - wy);
    const float w10 = (1.0f - wx) * wy;
    const float w11 = wx * wy;

    // ---- issue ALL loads into NAMED registers, then fence ----
    const size_t p00 = ((size_t)b * PLANE + (size_t)y0 * Wc + x0) * Cc;
    const h8* g0 = (const h8*)(wsp + p00);                    // v00(ch0-7,8-15), v01(...)
    const h8* g1 = (const h8*)(wsp + p00 + (size_t)Wc * Cc);  // v10, v11

    const h8 a0 = g0[0], a1 = g0[1], a2 = g0[2], a3 = g0[3];
    const h8 b0 = g1[0], b1 = g1[1], b2 = g1[2], b3 = g1[3];

    const size_t cb0 = (size_t)b * Cc * PLANE + pix;
    float cu[Cc];
    #pragma unroll
    for (int c = 0; c < Cc; ++c)
        cu[c] = __builtin_nontemporal_load(&cur[cb0 + (size_t)c * PLANE]);

    __builtin_amdgcn_sched_barrier(0);   // loads stay clustered above

    // ---- consume (all indices compile-time constant -> register code) ----
    #pragma unroll
    for (int c = 0; c < Cc; ++c) {
        const float v00 = (float)(c < 8 ? a0[c & 7] : a1[c & 7]);
        const float v01 = (float)(c < 8 ? a2[c & 7] : a3[c & 7]);
        const float v10 = (float)(c < 8 ? b0[c & 7] : b1[c & 7]);
        const float v11 = (float)(c < 8 ? b2[c & 7] : b3[c & 7]);
        const float warped = v00 * w00 + v01 * w01 + v10 * w10 + v11 * w11;
        __builtin_nontemporal_store(ALPHA * warped + (1.0f - ALPHA) * cu[c],
                                    &out[cb0 + (size_t)c * PLANE]);
    }
}

// ---------------- fallback: R4 direct f32 gather (if ws too small) ----------------
constexpr int FNX = Wc / 64;          // 30
constexpr int FNY = Hc / 4;           // 270
constexpr int FNBLK = Bc * FNY * FNX; // 32400
constexpr int FCHUNK = FNBLK / NXCD;

__global__ __launch_bounds__(256) void TemporalEMA_fallback_kernel(
    const float* __restrict__ cur,
    const float* __restrict__ prev,
    const float* __restrict__ mv,
    float* __restrict__ out)
{
    const int bid  = blockIdx.x;
    const int work = (bid % NXCD) * FCHUNK + bid / NXCD;
    const int tx  = work % FNX;
    const int rem = work / FNX;
    const int ty  = rem % FNY;
    const int b   = rem / FNY;
    const int lw = threadIdx.x & 63;
    const int lh = threadIdx.x >> 6;
    const int w  = tx * 64 + lw;
    const int h  = ty * 4 + lh;
    const size_t pix = (size_t)h * Wc + w;

    const float mvx = mv[((size_t)b * 2 + 0) * PLANE + pix];
    const float mvy = mv[((size_t)b * 2 + 1) * PLANE + pix];
    const float sxk = (float)(Wc - 1) / (float)Wc;
    const float syk = (float)(Hc - 1) / (float)Hc;
    float px = fminf(fmaxf((float)w - mvx * sxk, 0.0f), (float)(Wc - 1));
    float py = fminf(fmaxf((float)h - mvy * syk, 0.0f), (float)(Hc - 1));
    const int x0 = min((int)floorf(px), Wc - 2);
    const int y0 = min((int)floorf(py), Hc - 2);
    const float wx = px - (float)x0;
    const float wy = py - (float)y0;
    const float w00 = (1.0f - wx) * (1.0f - wy);
    const float w01 = wx * (1.0f - wy);
    const float w10 = (1.0f - wx) * wy;
    const float w11 = wx * wy;
    const size_t o0 = (size_t)y0 * Wc + x0;
    const size_t o1 = o0 + Wc;
    const size_t base_b = (size_t)b * Cc * PLANE;

    #pragma unroll
    for (int cg = 0; cg < Cc; cg += 4) {
        f2 p0[4], p1[4];
        float cu[4];
        #pragma unroll
        for (int j = 0; j < 4; ++j) {
            const size_t cb = base_b + (size_t)(cg + j) * PLANE;
            p0[j] = *(const f2*)(prev + cb + o0);
            p1[j] = *(const f2*)(prev + cb + o1);
            cu[j] = cur[cb + pix];
        }
        #pragma unroll
        for (int j = 0; j < 4; ++j) {
            const size_t cb = base_b + (size_t)(cg + j) * PLANE;
            const float warped = p0[j].x * w00 + p0[j].y * w01
                               + p1[j].x * w10 + p1[j].y * w11;
            out[cb + pix] = ALPHA * warped + (1.0f - ALPHA) * cu[j];
        }
    }
}

extern "C" void kernel_launch(void* const* d_in, const int* in_sizes, int n_in,
                              void* d_out, int out_size, void* d_ws, size_t ws_size,
                              hipStream_t stream) {
    const float* cur  = (const float*)d_in[0];
    const float* prev = (const float*)d_in[1];
    const float* mv   = (const float*)d_in[2];
    float* out = (float*)d_out;

    if (ws_size >= WS_NEED) {
        __half* ws = (__half*)d_ws;
        TemporalEMA_repack_kernel<<<Bc * BLK_PER_B, 256, 0, stream>>>(prev, ws);
        TemporalEMA_73194832658797_kernel<<<NBLK, 512, 0, stream>>>(cur, ws, mv, out);
    } else {
        TemporalEMA_fallback_kernel<<<FNBLK, 256, 0, stream>>>(cur, prev, mv, out);
    }
}